// Round 4
// baseline (28.665 us; speedup 1.0000x reference)
//
#include <hip/hip_runtime.h>

// DynamicMaskHead, two-kernel split:
//   A) dmh_mask: per-instance MLP over the 96x128 crop -> pre-sigmoid mask
//      into d_ws (128*96*128 f32 = 6.29 MB). No LDS, no redundancy.
//   B) dmh_upsample: bilinear 2x -> 192x256, sigmoid, float4 stores.
// Fallback single fused kernel if ws_size is too small (never expected).

#define HH 192
#define WW 256
#define IH 96
#define IW 128
#define HW (HH * WW)
#define MHW (IH * IW)

__device__ __forceinline__ void inst_setup(
    const float* __restrict__ locs, const int* __restrict__ im_inds,
    const int* __restrict__ fpn, int s, int inst,
    float& ix, float& iy, float& inv_soi, int& im, int& gx, int& gy)
{
    ix = locs[2 * inst + 0];
    iy = locs[2 * inst + 1];
    inv_soi = 1.0f / (float)(64 << fpn[inst]);
    im = im_inds[inst];
    const float nlx = ix * 0.125f;
    const float nly = iy * 0.125f;
    gx = (int)floorf(fminf(fmaxf(nlx, 0.0f), (float)(WW - 1)) / (float)(WW / 2));
    gy = (int)floorf(fminf(fmaxf(nly, 0.0f), (float)(HH - 1)) / (float)(HH / 2));
}

__device__ __forceinline__ float mlp_px(
    const float* __restrict__ p, const float* f, float relx, float rely)
{
    float a[8];
    #pragma unroll
    for (int k = 0; k < 8; ++k) {
        float acc = p[152 + k];
        acc = fmaf(p[k * 10 + 0], relx, acc);
        acc = fmaf(p[k * 10 + 1], rely, acc);
        #pragma unroll
        for (int c = 0; c < 8; ++c)
            acc = fmaf(p[k * 10 + 2 + c], f[c], acc);
        a[k] = fmaxf(acc, 0.0f);
    }
    float b[8];
    #pragma unroll
    for (int k = 0; k < 8; ++k) {
        float acc = p[160 + k];
        #pragma unroll
        for (int c = 0; c < 8; ++c)
            acc = fmaf(p[80 + k * 8 + c], a[c], acc);
        b[k] = fmaxf(acc, 0.0f);
    }
    float acc = p[168];
    #pragma unroll
    for (int c = 0; c < 8; ++c)
        acc = fmaf(p[144 + c], b[c], acc);
    return acc;
}

// ---------- Kernel A: mask (pre-sigmoid), grid (24, 128), 256 thr ----------
__global__ __launch_bounds__(256, 8) void dmh_mask(
    const float* __restrict__ mf, const float* __restrict__ params,
    const float* __restrict__ locs, const int* __restrict__ im_inds,
    const int* __restrict__ fpn, const int* __restrict__ stride_p,
    float* __restrict__ mask)
{
    const int inst = blockIdx.y;
    const int tid  = threadIdx.x;
    const int s    = stride_p[0];
    const int sh   = s >> 1;

    float ix, iy, inv_soi; int im, gx, gy;
    inst_setup(locs, im_inds, fpn, s, inst, ix, iy, inv_soi, im, gx, gy);
    const float* __restrict__ p = params + inst * 169;

    const int col2 = (tid & 63) * 2;            // 0..126
    const int gr   = blockIdx.x * 4 + (tid >> 6); // mask row 0..95
    const int h    = gy * IH + gr;              // feature row
    const float rely = (iy - (float)(h * s + sh)) * inv_soi;

    const float* fbase = mf + ((size_t)(im * 8) * HH + h) * WW + gx * IW + col2;
    float2 f2[8];
    #pragma unroll
    for (int c = 0; c < 8; ++c)
        f2[c] = *(const float2*)(fbase + (size_t)c * HW);

    float f0[8], f1[8];
    #pragma unroll
    for (int c = 0; c < 8; ++c) { f0[c] = f2[c].x; f1[c] = f2[c].y; }

    const float relx0 = (ix - (float)((gx * IW + col2) * s + sh)) * inv_soi;
    const float relx1 = relx0 - (float)s * inv_soi;

    float2 res;
    res.x = mlp_px(p, f0, relx0, rely);
    res.y = mlp_px(p, f1, relx1, rely);

    *(float2*)&mask[(size_t)inst * MHW + gr * IW + col2] = res;
}

// ---------- Kernel B: upsample + sigmoid, grid (48, 128), 256 thr ----------
__global__ __launch_bounds__(256, 8) void dmh_upsample(
    const float* __restrict__ mask, float* __restrict__ out)
{
    const int inst = blockIdx.y;
    const int tid  = threadIdx.x;
    const int col4 = (tid & 63) * 4;             // 0..252
    const int orow = blockIdx.x * 4 + (tid >> 6); // 0..191

    const float hpos = (float)orow * (95.0f / 191.0f);
    int hlo = (int)hpos; if (hlo > IH - 2) hlo = IH - 2;
    const float fh = hpos - (float)hlo;

    const float* mrow = mask + (size_t)inst * MHW + hlo * IW;

    float4 v;
    float* vv = &v.x;
    #pragma unroll
    for (int j = 0; j < 4; ++j) {
        const float wpos = (float)(col4 + j) * (127.0f / 255.0f);
        int wlo = (int)wpos; if (wlo > IW - 2) wlo = IW - 2;
        const float fw = wpos - (float)wlo;

        const float v00 = mrow[wlo];
        const float v01 = mrow[wlo + 1];
        const float v10 = mrow[wlo + IW];
        const float v11 = mrow[wlo + IW + 1];

        const float top = fmaf(fw, v01 - v00, v00);
        const float bot = fmaf(fw, v11 - v10, v10);
        const float val = fmaf(fh, bot - top, top);
        vv[j] = 1.0f / (1.0f + __expf(-val));
    }
    *(float4*)(out + (size_t)inst * HW + (size_t)orow * WW + col4) = v;
}

// ---------- Fallback fused kernel (if ws too small; not expected) ----------
__global__ __launch_bounds__(256, 6) void dmh_fused(
    const float* __restrict__ mf, const float* __restrict__ params,
    const float* __restrict__ locs, const int* __restrict__ im_inds,
    const int* __restrict__ fpn, const int* __restrict__ stride_p,
    float* __restrict__ out)
{
    __shared__ float m[8 * IW];
    const int bx = blockIdx.x;
    const int inst = bx >> 4;
    const int q = bx & 15;
    const int tid = threadIdx.x;
    const int s = stride_p[0];
    const int sh = s >> 1;

    float ix, iy, inv_soi; int im, gx, gy;
    inst_setup(locs, im_inds, fpn, s, inst, ix, iy, inv_soi, im, gx, gy);
    const float* __restrict__ p = params + inst * 169;

    const int orow0 = q * 12;
    const int ms = (int)((float)orow0 * (95.0f / 191.0f));
    {
        const int col2 = (tid & 63) * 2;
        const int r = tid >> 6;
        #pragma unroll
        for (int rr = 0; rr < 2; ++rr) {
            int gr = ms + r + rr * 4; if (gr > IH - 1) gr = IH - 1;
            const int h = gy * IH + gr;
            const float rely = (iy - (float)(h * s + sh)) * inv_soi;
            const float* fbase = mf + ((size_t)(im * 8) * HH + h) * WW + gx * IW + col2;
            float f0[8], f1[8];
            #pragma unroll
            for (int c = 0; c < 8; ++c) {
                float2 t = *(const float2*)(fbase + (size_t)c * HW);
                f0[c] = t.x; f1[c] = t.y;
            }
            const float relx0 = (ix - (float)((gx * IW + col2) * s + sh)) * inv_soi;
            const float relx1 = relx0 - (float)s * inv_soi;
            m[(r + rr * 4) * IW + col2]     = mlp_px(p, f0, relx0, rely);
            m[(r + rr * 4) * IW + col2 + 1] = mlp_px(p, f1, relx1, rely);
        }
    }
    __syncthreads();
    {
        const int ocol = tid;
        const float wpos = (float)ocol * (127.0f / 255.0f);
        int wlo = (int)wpos; if (wlo > IW - 2) wlo = IW - 2;
        const float fw = wpos - (float)wlo;
        float* op = out + (size_t)inst * HW + (size_t)orow0 * WW + ocol;
        #pragma unroll
        for (int r = 0; r < 12; ++r) {
            const float hpos = (float)(orow0 + r) * (95.0f / 191.0f);
            int hlo = (int)hpos; if (hlo > IH - 2) hlo = IH - 2;
            const float fh = hpos - (float)hlo;
            const int rl = hlo - ms;
            const float* mp = &m[rl * IW + wlo];
            const float v00 = mp[0], v01 = mp[1], v10 = mp[IW], v11 = mp[IW + 1];
            const float top = fmaf(fw, v01 - v00, v00);
            const float bot = fmaf(fw, v11 - v10, v10);
            const float val = fmaf(fh, bot - top, top);
            op[(size_t)r * WW] = 1.0f / (1.0f + __expf(-val));
        }
    }
}

extern "C" void kernel_launch(void* const* d_in, const int* in_sizes, int n_in,
                              void* d_out, int out_size, void* d_ws, size_t ws_size,
                              hipStream_t stream) {
    const float* mf       = (const float*)d_in[0];
    const float* params   = (const float*)d_in[1];
    const float* locs     = (const float*)d_in[2];
    const int*   im_inds  = (const int*)d_in[3];
    const int*   fpn      = (const int*)d_in[4];
    const int*   stride_p = (const int*)d_in[5];
    float*       out      = (float*)d_out;

    const size_t mask_bytes = (size_t)128 * MHW * sizeof(float);
    if (ws_size >= mask_bytes) {
        float* mask = (float*)d_ws;
        dmh_mask<<<dim3(24, 128), dim3(256), 0, stream>>>(
            mf, params, locs, im_inds, fpn, stride_p, mask);
        dmh_upsample<<<dim3(48, 128), dim3(256), 0, stream>>>(mask, out);
    } else {
        dmh_fused<<<dim3(2048), dim3(256), 0, stream>>>(
            mf, params, locs, im_inds, fpn, stride_p, out);
    }
}